// Round 4
// baseline (501.655 us; speedup 1.0000x reference)
//
#include <hip/hip_runtime.h>
#include <hip/hip_bf16.h>
#include <math.h>

#define NN 131072
#define BSEG 16
#define CCH 128
#define KK 16
#define EPSF 1e-9f
#define XST 136   // LDS row stride in bf16 elements (128 + 8 pad, 16B aligned)

// d_out layout (floats): out[B*K*C]=32768 | s[N*K]=2097152 | mu[B*K*2]=512 | losses[9]
#define OFF_S   32768
#define OFF_MU  2129920
#define OFF_L   2130432

// ws layout (floats):
//  [0]                      is64 flag
//  [SL_BASE .. +50*4096)    per-wave slots: row r, col c at SL_BASE + r*4096 + c
//                           rows: 0=seg tag, 1..16=sum_s[k], 17..48=sum_pos[2k+d], 49=ent
//                           col = (blockIdx*2 + wave)*2 + {0=primary,1=secondary}
//  [ST_BASE .. +4*32768)    4 staged copies of out accumulator (atomics, blockIdx&3)
#define SL_BASE 1024
#define SL_COLS 4096
#define ST_BASE (SL_BASE + 50 * SL_COLS)   // 205824
#define NST 4
#define ST_SZ (BSEG * KK * CCH)            // 32768

typedef __bf16 bf16x8 __attribute__((ext_vector_type(8)));
typedef float  f32x4  __attribute__((ext_vector_type(4)));
typedef float  f32x16 __attribute__((ext_vector_type(16)));

__device__ __forceinline__ int load_batch(const void* bptr, int n, int is64) {
    if (is64) return (int)((const long long*)bptr)[n];
    return ((const int*)bptr)[n];
}

__device__ __forceinline__ float wave_sum(float v) {
#pragma unroll
    for (int o = 32; o > 0; o >>= 1) v += __shfl_xor(v, o, 64);
    return v;
}

__device__ __forceinline__ bf16x8 pack8(float4 a, float4 b) {
    bf16x8 v;
    v[0] = (__bf16)a.x; v[1] = (__bf16)a.y; v[2] = (__bf16)a.z; v[3] = (__bf16)a.w;
    v[4] = (__bf16)b.x; v[5] = (__bf16)b.y; v[6] = (__bf16)b.z; v[7] = (__bf16)b.w;
    return v;
}

__global__ void k_zero(float* __restrict__ ws, const int* __restrict__ b32) {
    int i = blockIdx.x * 256 + threadIdx.x;   // grid 512*256 = 131072 == NST*ST_SZ
    ws[ST_BASE + i] = 0.0f;
    if (i == 0) ws[0] = (b32[NN - 1] == 0) ? 1.0f : 0.0f;  // int64 high word at odd idx => 0
}

__global__ __launch_bounds__(256, 2) void k_fused(
    const float* __restrict__ x, const void* __restrict__ batch,
    const float* __restrict__ pos, const float* __restrict__ gumbel,
    const float* __restrict__ W1, const float* __restrict__ b1,
    const float* __restrict__ W2, const float* __restrict__ b2,
    const float* __restrict__ scaling, const float* __restrict__ active_mask,
    float* __restrict__ s_out, float* __restrict__ ws)
{
    __shared__ __align__(16) __bf16 x_lds[128 * XST];
    __shared__ __align__(16) __bf16 h_lds[128 * XST];  // row n: bytes [192,256) hold logits f32 after h consumed
    __shared__ __align__(16) __bf16 sT[16 * XST];
    __shared__ int bsegs[128];

    const int tid  = threadIdx.x;
    const int lane = tid & 63;
    const int wv   = tid >> 6;
    const int n0   = blockIdx.x * 128;
    const int is64 = (int)ws[0];

    if (tid < 128) bsegs[tid] = load_batch(batch, n0 + tid, is64);

    // ---- tid<128: prefetch own node's gumbel row (held through the GEMMs) ----
    float4 ga0, ga1, ga2, ga3;
    if (tid < 128) {
        const float4* gp = (const float4*)(gumbel + (size_t)(n0 + tid) * KK);
        ga0 = gp[0]; ga1 = gp[1]; ga2 = gp[2]; ga3 = gp[3];
    }

    // ---- stage x -> LDS bf16 ----
    {
        const float4* xg = (const float4*)(x + (size_t)n0 * CCH);
#pragma unroll
        for (int i = 0; i < 8; i++) {
            int p = i * 256 + tid;          // pair of float4 = 8 elements
            float4 a = xg[2 * p], b = xg[2 * p + 1];
            *(bf16x8*)&x_lds[(p >> 4) * XST + (p & 15) * 8] = pack8(a, b);
        }
    }
    __syncthreads();

    // ================= GEMM1: h = relu(x @ W1^T + b1), 32x32x16 =================
    {
        bf16x8 bfr[8];
        const float* wrow = W1 + (size_t)(wv * 32 + (lane & 31)) * CCH + (lane >> 5) * 8;
#pragma unroll
        for (int ks = 0; ks < 8; ks++) {
            float4 u = *(const float4*)(wrow + ks * 16);
            float4 v = *(const float4*)(wrow + ks * 16 + 4);
            bfr[ks] = pack8(u, v);
        }
        f32x16 acc[4];
#pragma unroll
        for (int mt = 0; mt < 4; mt++)
#pragma unroll
            for (int r = 0; r < 16; r++) acc[mt][r] = 0.0f;

#pragma unroll
        for (int ks = 0; ks < 8; ks++) {
#pragma unroll
            for (int mt = 0; mt < 4; mt++) {
                bf16x8 a = *(bf16x8*)&x_lds[(size_t)(mt * 32 + (lane & 31)) * XST + ks * 16 + (lane >> 5) * 8];
                acc[mt] = __builtin_amdgcn_mfma_f32_32x32x16_bf16(a, bfr[ks], acc[mt], 0, 0, 0);
            }
        }
        const float b1j = b1[wv * 32 + (lane & 31)];
#pragma unroll
        for (int mt = 0; mt < 4; mt++)
#pragma unroll
            for (int r = 0; r < 16; r++) {
                int node = mt * 32 + (r & 3) + 8 * (r >> 2) + 4 * (lane >> 5);
                h_lds[(size_t)node * XST + wv * 32 + (lane & 31)] = (__bf16)fmaxf(acc[mt][r] + b1j, 0.0f);
            }
    }
    __syncthreads();

    // ================= GEMM2: logits = h @ W2^T, 16x16x32 =================
    {
        f32x4 acc2[2];
#pragma unroll
        for (int t = 0; t < 2; t++)
#pragma unroll
            for (int r = 0; r < 4; r++) acc2[t][r] = 0.0f;

#pragma unroll
        for (int ks = 0; ks < 4; ks++) {
            const float* w2row = W2 + (size_t)(lane & 15) * CCH + ks * 32 + (lane >> 4) * 8;
            float4 u = *(const float4*)w2row;
            float4 v = *(const float4*)(w2row + 4);
            bf16x8 bw = pack8(u, v);
#pragma unroll
            for (int t = 0; t < 2; t++) {
                int tile = wv * 2 + t;
                bf16x8 a = *(bf16x8*)&h_lds[(size_t)(tile * 16 + (lane & 15)) * XST + ks * 32 + (lane >> 4) * 8];
                acc2[t] = __builtin_amdgcn_mfma_f32_16x16x32_bf16(a, bw, acc2[t], 0, 0, 0);
            }
        }
        // write logits f32 into this wave's own (now dead) h rows, byte offset 192
#pragma unroll
        for (int t = 0; t < 2; t++) {
#pragma unroll
            for (int r = 0; r < 4; r++) {
                int node = (wv * 2 + t) * 16 + (lane >> 4) * 4 + r;
                float* lp = (float*)((char*)h_lds + (size_t)node * (XST * 2) + 192);
                lp[lane & 15] = acc2[t][r];
            }
        }
    }
    __syncthreads();

    // ================= softmax + s write + per-wave segment slots (threads<128) ==========
    if (tid < 128) {
        const int n = n0 + tid;
        const char* rb = (const char*)h_lds + (size_t)tid * (XST * 2);
        float lg[16], gu[16];
#pragma unroll
        for (int i = 0; i < 4; i++) {
            float4 t = *(const float4*)(rb + 192 + 16 * i);
            lg[4 * i] = t.x; lg[4 * i + 1] = t.y; lg[4 * i + 2] = t.z; lg[4 * i + 3] = t.w;
        }
        gu[0] = ga0.x; gu[1] = ga0.y; gu[2]  = ga0.z; gu[3]  = ga0.w;
        gu[4] = ga1.x; gu[5] = ga1.y; gu[6]  = ga1.z; gu[7]  = ga1.w;
        gu[8] = ga2.x; gu[9] = ga2.y; gu[10] = ga2.z; gu[11] = ga2.w;
        gu[12] = ga3.x; gu[13] = ga3.y; gu[14] = ga3.z; gu[15] = ga3.w;

        const float sc = scaling[0];
        float m = -1e30f;
#pragma unroll
        for (int k = 0; k < KK; k++) {
            float v = (lg[k] + b2[k]) * sc;
            if (active_mask[k] == 0.0f) v = -1e9f;
            v += gu[k];                 // TAU == 1.0
            lg[k] = v;
            m = fmaxf(m, v);
        }
        float ssum = 0.0f;
#pragma unroll
        for (int k = 0; k < KK; k++) { lg[k] = expf(lg[k] - m); ssum += lg[k]; }
        const float inv = 1.0f / ssum;
        float sarr[16];
#pragma unroll
        for (int k = 0; k < KK; k++) sarr[k] = lg[k] * inv;

        float4* srow = (float4*)(s_out + (size_t)n * KK);
#pragma unroll
        for (int i = 0; i < 4; i++) {
            float4 t;
            t.x = sarr[4 * i]; t.y = sarr[4 * i + 1]; t.z = sarr[4 * i + 2]; t.w = sarr[4 * i + 3];
            srow[i] = t;
        }
#pragma unroll
        for (int k = 0; k < KK; k++) sT[k * XST + tid] = (__bf16)sarr[k];

        float ent = 0.0f;
#pragma unroll
        for (int k = 0; k < KK; k++) ent += sarr[k] * logf(sarr[k] + EPSF);

        const float2 p = ((const float2*)pos)[n];
        const int bi = bsegs[tid];
        const int b0 = __shfl(bi, 0, 64);
        const int b1s = __shfl(bi, 63, 64);
        const float prim = (bi == b0) ? 1.0f : 0.0f;
        const int gw = (blockIdx.x << 1) + (tid >> 6);
        float* col0 = ws + SL_BASE + (gw << 1);
        float* col1 = col0 + 1;

        if (lane == 0) { col0[0] = (float)b0; col1[0] = (float)b1s; }
#pragma unroll
        for (int k = 0; k < KK; k++) {
            float v = wave_sum(sarr[k] * prim);
            if (lane == 0) col0[(1 + k) * SL_COLS] = v;
        }
#pragma unroll
        for (int k = 0; k < KK; k++) {
            float vx = wave_sum(sarr[k] * p.x * prim);
            float vy = wave_sum(sarr[k] * p.y * prim);
            if (lane == 0) {
                col0[(17 + 2 * k) * SL_COLS] = vx;
                col0[(18 + 2 * k) * SL_COLS] = vy;
            }
        }
        {
            float e = wave_sum(ent * prim);
            if (lane == 0) col0[49 * SL_COLS] = e;
        }

        if (b0 != b1s) {
            const float sec = 1.0f - prim;
#pragma unroll
            for (int k = 0; k < KK; k++) {
                float v = wave_sum(sarr[k] * sec);
                if (lane == 0) col1[(1 + k) * SL_COLS] = v;
            }
#pragma unroll
            for (int k = 0; k < KK; k++) {
                float vx = wave_sum(sarr[k] * p.x * sec);
                float vy = wave_sum(sarr[k] * p.y * sec);
                if (lane == 0) {
                    col1[(17 + 2 * k) * SL_COLS] = vx;
                    col1[(18 + 2 * k) * SL_COLS] = vy;
                }
            }
            float e = wave_sum(ent * sec);
            if (lane == 0) col1[49 * SL_COLS] = e;
        } else if (lane == 0) {
#pragma unroll
            for (int r = 1; r < 50; r++) col1[r * SL_COLS] = 0.0f;
        }
    }
    __syncthreads();

    // ================= pooling: stage[g][b,k,c] += s[n,k]*x[n,c] via 16x16x32 ============
    {
        float* stg = ws + ST_BASE + (size_t)(blockIdx.x & (NST - 1)) * ST_SZ;
        const int bfirst = bsegs[0], blast = bsegs[127];
        for (int seg = bfirst; seg <= blast; seg++) {
            const bool masked = (bfirst != blast);
            f32x4 pacc[2];
#pragma unroll
            for (int t = 0; t < 2; t++)
#pragma unroll
                for (int r = 0; r < 4; r++) pacc[t][r] = 0.0f;

#pragma unroll
            for (int ks = 0; ks < 4; ks++) {
                bf16x8 a = *(bf16x8*)&sT[(size_t)(lane & 15) * XST + ks * 32 + (lane >> 4) * 8];
                if (masked) {
#pragma unroll
                    for (int i = 0; i < 8; i++) {
                        int nd = ks * 32 + (lane >> 4) * 8 + i;
                        if (bsegs[nd] != seg) a[i] = (__bf16)0.0f;
                    }
                }
#pragma unroll
                for (int t = 0; t < 2; t++) {
                    int ct = wv * 2 + t;
                    bf16x8 bx;
#pragma unroll
                    for (int i = 0; i < 8; i++)
                        bx[i] = x_lds[(size_t)(ks * 32 + (lane >> 4) * 8 + i) * XST + ct * 16 + (lane & 15)];
                    pacc[t] = __builtin_amdgcn_mfma_f32_16x16x32_bf16(a, bx, pacc[t], 0, 0, 0);
                }
            }
#pragma unroll
            for (int t = 0; t < 2; t++) {
                int c = (wv * 2 + t) * 16 + (lane & 15);
#pragma unroll
                for (int r = 0; r < 4; r++) {
                    int k = (lane >> 4) * 4 + r;
                    atomicAdd(&stg[((size_t)seg * KK + k) * CCH + c], pacc[t][r]);
                }
            }
        }
    }
}

__global__ __launch_bounds__(256) void k_reduce(const float* __restrict__ ws,
                                                float* __restrict__ out) {
    int i = blockIdx.x * 256 + threadIdx.x;    // [0, 8192) float4 index
    const float4* s0 = (const float4*)(ws + ST_BASE);
    const float4* s1 = (const float4*)(ws + ST_BASE + ST_SZ);
    const float4* s2 = (const float4*)(ws + ST_BASE + 2 * ST_SZ);
    const float4* s3 = (const float4*)(ws + ST_BASE + 3 * ST_SZ);
    float4 a = s0[i], b = s1[i], c = s2[i], d = s3[i];
    float4 r;
    r.x = (a.x + b.x) + (c.x + d.x);
    r.y = (a.y + b.y) + (c.y + d.y);
    r.z = (a.z + b.z) + (c.z + d.z);
    r.w = (a.w + b.w) + (c.w + d.w);
    ((float4*)out)[i] = r;
}

__global__ __launch_bounds__(256) void k_final(
    const float* __restrict__ ws, const float* __restrict__ active_mask,
    float* __restrict__ mu_out, float* __restrict__ losses)
{
    __shared__ float lsum[256];
    __shared__ float lpos[512];
    __shared__ float lent[1];
    __shared__ float smu[512];
    __shared__ float savg[16];
    __shared__ float red[256];
    const int tid = threadIdx.x;

    lsum[tid] = 0.0f; lpos[tid] = 0.0f; lpos[256 + tid] = 0.0f;
    if (tid == 0) lent[0] = 0.0f;
    __syncthreads();

    for (int c = tid; c < SL_COLS; c += 256) {
        int seg = (int)ws[SL_BASE + c];
#pragma unroll
        for (int k = 0; k < 16; k++)
            atomicAdd(&lsum[seg * 16 + k], ws[SL_BASE + (1 + k) * SL_COLS + c]);
#pragma unroll
        for (int k = 0; k < 32; k++)
            atomicAdd(&lpos[seg * 32 + k], ws[SL_BASE + (17 + k) * SL_COLS + c]);
        atomicAdd(&lent[0], ws[SL_BASE + 49 * SL_COLS + c]);
    }
    __syncthreads();

    if (tid < 16) {
        float a = 0.0f;
#pragma unroll
        for (int b = 0; b < 16; b++) a += lsum[b * 16 + tid];
        savg[tid] = a / (float)NN;
    }
    for (int i = tid; i < 512; i += 256) {
        int sk = i >> 1;   // b*16+k
        float v = lpos[i] / (lsum[sk] + EPSF);
        smu[i] = v;
        mu_out[i] = v;
    }
    __syncthreads();

    float rep = 0.0f;
    for (int t = tid; t < 4096; t += 256) {
        int b = t >> 8, i = (t >> 4) & 15, j = t & 15;
        if (i != j) {
            float dx = smu[b * 32 + i * 2]     - smu[b * 32 + j * 2];
            float dy = smu[b * 32 + i * 2 + 1] - smu[b * 32 + j * 2 + 1];
            rep += 1.0f / (dx * dx + dy * dy + 1.0f);
        }
    }
    red[tid] = rep;
    __syncthreads();
    for (int st = 128; st > 0; st >>= 1) {
        if (tid < st) red[tid] += red[tid + st];
        __syncthreads();
    }

    if (tid == 0) {
        const float p = 1.0f / 16.0f;
        float separation = red[0] / (float)(16 * 15);
        float entropy = -lent[0] / (float)NN;
        float diversity = 0.f, pruning = 0.f, amsum = 0.f, collapse = 0.f, mean = 0.f;
        for (int k = 0; k < 16; k++) {
            float a = savg[k];
            diversity += p * logf(p / (a + EPSF));
            pruning += fabsf(a * (1.0f - active_mask[k]));
            amsum += active_mask[k];
            collapse += (a - p) * (a - p);
            mean += a;
        }
        pruning /= 16.0f;
        mean /= 16.0f;
        float var = 0.f;
        for (int k = 0; k < 16; k++) { float d = savg[k] - mean; var += d * d; }
        float balance = sqrtf(var / 16.0f);
        float sparsity = (amsum / 16.0f) * 0.01f;
        collapse *= 2.0f;
        losses[0] = entropy;   losses[1] = diversity; losses[2] = 0.0f;
        losses[3] = pruning;   losses[4] = sparsity;  losses[5] = 0.0f;
        losses[6] = collapse;  losses[7] = balance;   losses[8] = separation;
    }
}

extern "C" void kernel_launch(void* const* d_in, const int* in_sizes, int n_in,
                              void* d_out, int out_size, void* d_ws, size_t ws_size,
                              hipStream_t stream) {
    const float* x       = (const float*)d_in[0];
    const void*  batch   = d_in[1];
    const float* pos     = (const float*)d_in[2];
    const float* gumbel  = (const float*)d_in[3];
    const float* W1      = (const float*)d_in[4];
    const float* b1      = (const float*)d_in[5];
    const float* W2      = (const float*)d_in[6];
    const float* b2      = (const float*)d_in[7];
    const float* scaling = (const float*)d_in[8];
    const float* am      = (const float*)d_in[9];

    float* out      = (float*)d_out;
    float* s_sec    = out + OFF_S;
    float* mu_sec   = out + OFF_MU;
    float* loss_sec = out + OFF_L;
    float* wsf      = (float*)d_ws;

    k_zero<<<512, 256, 0, stream>>>(wsf, (const int*)batch);
    k_fused<<<NN / 128, 256, 0, stream>>>(x, batch, pos, gumbel, W1, b1, W2, b2,
                                          scaling, am, s_sec, wsf);
    k_reduce<<<32, 256, 0, stream>>>(wsf, out);
    k_final<<<1, 256, 0, stream>>>(wsf, am, mu_sec, loss_sec);
}

// Round 5
// 183.974 us; speedup vs baseline: 2.7268x; 2.7268x over previous
//
#include <hip/hip_runtime.h>
#include <hip/hip_bf16.h>
#include <math.h>

#define NN 131072
#define BSEG 16
#define CCH 128
#define KK 16
#define EPSF 1e-9f
#define XST 136   // LDS row stride in bf16 elements (128 + 8 pad, 16B aligned)

// d_out layout (floats): out[B*K*C]=32768 | s[N*K]=2097152 | mu[B*K*2]=512 | losses[9]
#define OFF_S   32768
#define OFF_MU  2129920
#define OFF_L   2130432

// ws layout (floats):
//  [0]                       is64 flag
//  [REDC_BASE .. +64*1024)   64 staged copies of the small-reduction block:
//                            addr 0..255 sum_s[seg*16+k], 256..767 sum_pos[seg*32+2k+d], 768 ent
//  [ST_BASE .. +4*32768)     4 staged copies of out accumulator (atomics, blockIdx&3)
#define REDC_BASE 1024
#define REDC_STRIDE 1024
#define NRED 64
#define ST_BASE (REDC_BASE + NRED * REDC_STRIDE)   // 66560
#define NST 4
#define ST_SZ (BSEG * KK * CCH)                    // 32768

typedef __bf16 bf16x8 __attribute__((ext_vector_type(8)));
typedef float  f32x4  __attribute__((ext_vector_type(4)));
typedef float  f32x16 __attribute__((ext_vector_type(16)));

__device__ __forceinline__ int load_batch(const void* bptr, int n, int is64) {
    if (is64) return (int)((const long long*)bptr)[n];
    return ((const int*)bptr)[n];
}

__device__ __forceinline__ float wave_sum(float v) {
#pragma unroll
    for (int o = 32; o > 0; o >>= 1) v += __shfl_xor(v, o, 64);
    return v;
}

__device__ __forceinline__ bf16x8 pack8(float4 a, float4 b) {
    bf16x8 v;
    v[0] = (__bf16)a.x; v[1] = (__bf16)a.y; v[2] = (__bf16)a.z; v[3] = (__bf16)a.w;
    v[4] = (__bf16)b.x; v[5] = (__bf16)b.y; v[6] = (__bf16)b.z; v[7] = (__bf16)b.w;
    return v;
}

__global__ void k_zero(float* __restrict__ ws, const int* __restrict__ b32) {
    int i = blockIdx.x * 256 + threadIdx.x;   // grid 768*256 = 196608 == NRED*1024 + NST*ST_SZ
    ws[REDC_BASE + i] = 0.0f;
    if (i == 0) ws[0] = (b32[NN - 1] == 0) ? 1.0f : 0.0f;  // int64 high word at odd idx => 0
}

__global__ __launch_bounds__(256, 2) void k_fused(
    const float* __restrict__ x, const void* __restrict__ batch,
    const float* __restrict__ pos, const float* __restrict__ gumbel,
    const float* __restrict__ W1, const float* __restrict__ b1,
    const float* __restrict__ W2, const float* __restrict__ b2,
    const float* __restrict__ scaling, const float* __restrict__ active_mask,
    float* __restrict__ s_out, float* __restrict__ ws)
{
    __shared__ __align__(16) __bf16 x_lds[128 * XST];
    __shared__ __align__(16) __bf16 h_lds[128 * XST];  // row n: bytes [192,256) hold logits f32 after h consumed
    __shared__ __align__(16) __bf16 sT[16 * XST];
    __shared__ int bsegs[128];

    const int tid  = threadIdx.x;
    const int lane = tid & 63;
    const int wv   = tid >> 6;
    const int n0   = blockIdx.x * 128;
    const int is64 = (int)ws[0];

    if (tid < 128) bsegs[tid] = load_batch(batch, n0 + tid, is64);

    // ---- tid<128: prefetch own node's gumbel row (held through the GEMMs) ----
    float4 ga0, ga1, ga2, ga3;
    if (tid < 128) {
        const float4* gp = (const float4*)(gumbel + (size_t)(n0 + tid) * KK);
        ga0 = gp[0]; ga1 = gp[1]; ga2 = gp[2]; ga3 = gp[3];
    }

    // ---- stage x -> LDS bf16 ----
    {
        const float4* xg = (const float4*)(x + (size_t)n0 * CCH);
#pragma unroll
        for (int i = 0; i < 8; i++) {
            int p = i * 256 + tid;          // pair of float4 = 8 elements
            float4 a = xg[2 * p], b = xg[2 * p + 1];
            *(bf16x8*)&x_lds[(p >> 4) * XST + (p & 15) * 8] = pack8(a, b);
        }
    }
    __syncthreads();

    // ================= GEMM1: h = relu(x @ W1^T + b1), 32x32x16 =================
    {
        bf16x8 bfr[8];
        const float* wrow = W1 + (size_t)(wv * 32 + (lane & 31)) * CCH + (lane >> 5) * 8;
#pragma unroll
        for (int ks = 0; ks < 8; ks++) {
            float4 u = *(const float4*)(wrow + ks * 16);
            float4 v = *(const float4*)(wrow + ks * 16 + 4);
            bfr[ks] = pack8(u, v);
        }
        f32x16 acc[4];
#pragma unroll
        for (int mt = 0; mt < 4; mt++)
#pragma unroll
            for (int r = 0; r < 16; r++) acc[mt][r] = 0.0f;

#pragma unroll
        for (int ks = 0; ks < 8; ks++) {
#pragma unroll
            for (int mt = 0; mt < 4; mt++) {
                bf16x8 a = *(bf16x8*)&x_lds[(size_t)(mt * 32 + (lane & 31)) * XST + ks * 16 + (lane >> 5) * 8];
                acc[mt] = __builtin_amdgcn_mfma_f32_32x32x16_bf16(a, bfr[ks], acc[mt], 0, 0, 0);
            }
        }
        const float b1j = b1[wv * 32 + (lane & 31)];
#pragma unroll
        for (int mt = 0; mt < 4; mt++)
#pragma unroll
            for (int r = 0; r < 16; r++) {
                int node = mt * 32 + (r & 3) + 8 * (r >> 2) + 4 * (lane >> 5);
                h_lds[(size_t)node * XST + wv * 32 + (lane & 31)] = (__bf16)fmaxf(acc[mt][r] + b1j, 0.0f);
            }
    }
    __syncthreads();

    // ================= GEMM2: logits = h @ W2^T, 16x16x32 =================
    {
        f32x4 acc2[2];
#pragma unroll
        for (int t = 0; t < 2; t++)
#pragma unroll
            for (int r = 0; r < 4; r++) acc2[t][r] = 0.0f;

#pragma unroll
        for (int ks = 0; ks < 4; ks++) {
            const float* w2row = W2 + (size_t)(lane & 15) * CCH + ks * 32 + (lane >> 4) * 8;
            float4 u = *(const float4*)w2row;
            float4 v = *(const float4*)(w2row + 4);
            bf16x8 bw = pack8(u, v);
#pragma unroll
            for (int t = 0; t < 2; t++) {
                int tile = wv * 2 + t;
                bf16x8 a = *(bf16x8*)&h_lds[(size_t)(tile * 16 + (lane & 15)) * XST + ks * 32 + (lane >> 4) * 8];
                acc2[t] = __builtin_amdgcn_mfma_f32_16x16x32_bf16(a, bw, acc2[t], 0, 0, 0);
            }
        }
        // write logits f32 into this wave's own (now dead) h rows, byte offset 192
#pragma unroll
        for (int t = 0; t < 2; t++) {
#pragma unroll
            for (int r = 0; r < 4; r++) {
                int node = (wv * 2 + t) * 16 + (lane >> 4) * 4 + r;
                float* lp = (float*)((char*)h_lds + (size_t)node * (XST * 2) + 192);
                lp[lane & 15] = acc2[t][r];
            }
        }
    }
    __syncthreads();

    // ======= softmax + s write + staged-copy segment reductions (threads<128) =======
    if (tid < 128) {
        const int n = n0 + tid;
        const char* rb = (const char*)h_lds + (size_t)tid * (XST * 2);
        float lg[16], gu[16];
#pragma unroll
        for (int i = 0; i < 4; i++) {
            float4 t = *(const float4*)(rb + 192 + 16 * i);
            lg[4 * i] = t.x; lg[4 * i + 1] = t.y; lg[4 * i + 2] = t.z; lg[4 * i + 3] = t.w;
        }
        gu[0] = ga0.x; gu[1] = ga0.y; gu[2]  = ga0.z; gu[3]  = ga0.w;
        gu[4] = ga1.x; gu[5] = ga1.y; gu[6]  = ga1.z; gu[7]  = ga1.w;
        gu[8] = ga2.x; gu[9] = ga2.y; gu[10] = ga2.z; gu[11] = ga2.w;
        gu[12] = ga3.x; gu[13] = ga3.y; gu[14] = ga3.z; gu[15] = ga3.w;

        const float sc = scaling[0];
        float m = -1e30f;
#pragma unroll
        for (int k = 0; k < KK; k++) {
            float v = (lg[k] + b2[k]) * sc;
            if (active_mask[k] == 0.0f) v = -1e9f;
            v += gu[k];                 // TAU == 1.0
            lg[k] = v;
            m = fmaxf(m, v);
        }
        float ssum = 0.0f;
#pragma unroll
        for (int k = 0; k < KK; k++) { lg[k] = expf(lg[k] - m); ssum += lg[k]; }
        const float inv = 1.0f / ssum;
        float sarr[16];
#pragma unroll
        for (int k = 0; k < KK; k++) sarr[k] = lg[k] * inv;

        float4* srow = (float4*)(s_out + (size_t)n * KK);
#pragma unroll
        for (int i = 0; i < 4; i++) {
            float4 t;
            t.x = sarr[4 * i]; t.y = sarr[4 * i + 1]; t.z = sarr[4 * i + 2]; t.w = sarr[4 * i + 3];
            srow[i] = t;
        }
#pragma unroll
        for (int k = 0; k < KK; k++) sT[k * XST + tid] = (__bf16)sarr[k];

        float ent = 0.0f;
#pragma unroll
        for (int k = 0; k < KK; k++) ent += sarr[k] * logf(sarr[k] + EPSF);

        const float2 p = ((const float2*)pos)[n];
        const int bi = bsegs[tid];
        const int b0 = __shfl(bi, 0, 64);
        const int b1s = __shfl(bi, 63, 64);
        const float prim = (bi == b0) ? 1.0f : 0.0f;
        float* rc = ws + REDC_BASE + (size_t)(blockIdx.x & (NRED - 1)) * REDC_STRIDE;

#pragma unroll
        for (int k = 0; k < KK; k++) {
            float v = wave_sum(sarr[k] * prim);
            if (lane == 0) atomicAdd(&rc[b0 * 16 + k], v);
        }
#pragma unroll
        for (int k = 0; k < KK; k++) {
            float vx = wave_sum(sarr[k] * p.x * prim);
            float vy = wave_sum(sarr[k] * p.y * prim);
            if (lane == 0) {
                atomicAdd(&rc[256 + b0 * 32 + 2 * k],     vx);
                atomicAdd(&rc[256 + b0 * 32 + 2 * k + 1], vy);
            }
        }
        {
            float e = wave_sum(ent * prim);
            if (lane == 0) atomicAdd(&rc[768], e);
        }

        if (b0 != b1s) {
            const float sec = 1.0f - prim;
#pragma unroll
            for (int k = 0; k < KK; k++) {
                float v = wave_sum(sarr[k] * sec);
                if (lane == 0) atomicAdd(&rc[b1s * 16 + k], v);
            }
#pragma unroll
            for (int k = 0; k < KK; k++) {
                float vx = wave_sum(sarr[k] * p.x * sec);
                float vy = wave_sum(sarr[k] * p.y * sec);
                if (lane == 0) {
                    atomicAdd(&rc[256 + b1s * 32 + 2 * k],     vx);
                    atomicAdd(&rc[256 + b1s * 32 + 2 * k + 1], vy);
                }
            }
            float e = wave_sum(ent * sec);
            if (lane == 0) atomicAdd(&rc[768], e);
        }
    }
    __syncthreads();

    // ================= pooling: stage[g][b,k,c] += s[n,k]*x[n,c] via 16x16x32 ============
    {
        float* stg = ws + ST_BASE + (size_t)(blockIdx.x & (NST - 1)) * ST_SZ;
        const int bfirst = bsegs[0], blast = bsegs[127];
        for (int seg = bfirst; seg <= blast; seg++) {
            const bool masked = (bfirst != blast);
            f32x4 pacc[2];
#pragma unroll
            for (int t = 0; t < 2; t++)
#pragma unroll
                for (int r = 0; r < 4; r++) pacc[t][r] = 0.0f;

#pragma unroll
            for (int ks = 0; ks < 4; ks++) {
                bf16x8 a = *(bf16x8*)&sT[(size_t)(lane & 15) * XST + ks * 32 + (lane >> 4) * 8];
                if (masked) {
#pragma unroll
                    for (int i = 0; i < 8; i++) {
                        int nd = ks * 32 + (lane >> 4) * 8 + i;
                        if (bsegs[nd] != seg) a[i] = (__bf16)0.0f;
                    }
                }
#pragma unroll
                for (int t = 0; t < 2; t++) {
                    int ct = wv * 2 + t;
                    bf16x8 bx;
#pragma unroll
                    for (int i = 0; i < 8; i++)
                        bx[i] = x_lds[(size_t)(ks * 32 + (lane >> 4) * 8 + i) * XST + ct * 16 + (lane & 15)];
                    pacc[t] = __builtin_amdgcn_mfma_f32_16x16x32_bf16(a, bx, pacc[t], 0, 0, 0);
                }
            }
#pragma unroll
            for (int t = 0; t < 2; t++) {
                int c = (wv * 2 + t) * 16 + (lane & 15);
#pragma unroll
                for (int r = 0; r < 4; r++) {
                    int k = (lane >> 4) * 4 + r;
                    atomicAdd(&stg[((size_t)seg * KK + k) * CCH + c], pacc[t][r]);
                }
            }
        }
    }
}

__global__ __launch_bounds__(256) void k_reduce(const float* __restrict__ ws,
                                                float* __restrict__ out) {
    int i = blockIdx.x * 256 + threadIdx.x;    // [0, 8192) float4 index
    const float4* s0 = (const float4*)(ws + ST_BASE);
    const float4* s1 = (const float4*)(ws + ST_BASE + ST_SZ);
    const float4* s2 = (const float4*)(ws + ST_BASE + 2 * ST_SZ);
    const float4* s3 = (const float4*)(ws + ST_BASE + 3 * ST_SZ);
    float4 a = s0[i], b = s1[i], c = s2[i], d = s3[i];
    float4 r;
    r.x = (a.x + b.x) + (c.x + d.x);
    r.y = (a.y + b.y) + (c.y + d.y);
    r.z = (a.z + b.z) + (c.z + d.z);
    r.w = (a.w + b.w) + (c.w + d.w);
    ((float4*)out)[i] = r;
}

__global__ __launch_bounds__(256) void k_final(
    const float* __restrict__ ws, const float* __restrict__ active_mask,
    float* __restrict__ mu_out, float* __restrict__ losses)
{
    __shared__ float lsum[256];
    __shared__ float lpos[512];
    __shared__ float lent[1];
    __shared__ float smu[512];
    __shared__ float savg[16];
    __shared__ float red[256];
    const int tid = threadIdx.x;

    // reduce the 64 staged copies: thread t owns addresses t, t+256, t+512 (769 addrs)
    for (int a = tid; a < 769; a += 256) {
        float acc = 0.0f;
#pragma unroll 8
        for (int c = 0; c < NRED; c++) acc += ws[REDC_BASE + c * REDC_STRIDE + a];
        if (a < 256) lsum[a] = acc;
        else if (a < 768) lpos[a - 256] = acc;
        else lent[0] = acc;
    }
    __syncthreads();

    if (tid < 16) {
        float a = 0.0f;
#pragma unroll
        for (int b = 0; b < 16; b++) a += lsum[b * 16 + tid];
        savg[tid] = a / (float)NN;
    }
    for (int i = tid; i < 512; i += 256) {
        int sk = i >> 1;   // b*16+k
        float v = lpos[i] / (lsum[sk] + EPSF);
        smu[i] = v;
        mu_out[i] = v;
    }
    __syncthreads();

    float rep = 0.0f;
    for (int t = tid; t < 4096; t += 256) {
        int b = t >> 8, i = (t >> 4) & 15, j = t & 15;
        if (i != j) {
            float dx = smu[b * 32 + i * 2]     - smu[b * 32 + j * 2];
            float dy = smu[b * 32 + i * 2 + 1] - smu[b * 32 + j * 2 + 1];
            rep += 1.0f / (dx * dx + dy * dy + 1.0f);
        }
    }
    red[tid] = rep;
    __syncthreads();
    for (int st = 128; st > 0; st >>= 1) {
        if (tid < st) red[tid] += red[tid + st];
        __syncthreads();
    }

    if (tid == 0) {
        const float p = 1.0f / 16.0f;
        float separation = red[0] / (float)(16 * 15);
        float entropy = -lent[0] / (float)NN;
        float diversity = 0.f, pruning = 0.f, amsum = 0.f, collapse = 0.f, mean = 0.f;
        for (int k = 0; k < 16; k++) {
            float a = savg[k];
            diversity += p * logf(p / (a + EPSF));
            pruning += fabsf(a * (1.0f - active_mask[k]));
            amsum += active_mask[k];
            collapse += (a - p) * (a - p);
            mean += a;
        }
        pruning /= 16.0f;
        mean /= 16.0f;
        float var = 0.f;
        for (int k = 0; k < 16; k++) { float d = savg[k] - mean; var += d * d; }
        float balance = sqrtf(var / 16.0f);
        float sparsity = (amsum / 16.0f) * 0.01f;
        collapse *= 2.0f;
        losses[0] = entropy;   losses[1] = diversity; losses[2] = 0.0f;
        losses[3] = pruning;   losses[4] = sparsity;  losses[5] = 0.0f;
        losses[6] = collapse;  losses[7] = balance;   losses[8] = separation;
    }
}

extern "C" void kernel_launch(void* const* d_in, const int* in_sizes, int n_in,
                              void* d_out, int out_size, void* d_ws, size_t ws_size,
                              hipStream_t stream) {
    const float* x       = (const float*)d_in[0];
    const void*  batch   = d_in[1];
    const float* pos     = (const float*)d_in[2];
    const float* gumbel  = (const float*)d_in[3];
    const float* W1      = (const float*)d_in[4];
    const float* b1      = (const float*)d_in[5];
    const float* W2      = (const float*)d_in[6];
    const float* b2      = (const float*)d_in[7];
    const float* scaling = (const float*)d_in[8];
    const float* am      = (const float*)d_in[9];

    float* out      = (float*)d_out;
    float* s_sec    = out + OFF_S;
    float* mu_sec   = out + OFF_MU;
    float* loss_sec = out + OFF_L;
    float* wsf      = (float*)d_ws;

    k_zero<<<768, 256, 0, stream>>>(wsf, (const int*)batch);
    k_fused<<<NN / 128, 256, 0, stream>>>(x, batch, pos, gumbel, W1, b1, W2, b2,
                                          scaling, am, s_sec, wsf);
    k_reduce<<<32, 256, 0, stream>>>(wsf, out);
    k_final<<<1, 256, 0, stream>>>(wsf, am, mu_sec, loss_sec);
}